// Round 3
// baseline (243.403 us; speedup 1.0000x reference)
//
#include <hip/hip_runtime.h>

typedef __attribute__((ext_vector_type(8))) short bf16x8;
typedef __attribute__((ext_vector_type(4))) float f32x4;
typedef __attribute__((ext_vector_type(2))) unsigned int u32x2;

#define B_N 8
#define S_N 2048
#define D_N 128
#define W_N 16
#define G_N 512

// round-to-nearest-even fp32 -> bf16
__device__ __forceinline__ short f2bf(float f) {
  union { float f; unsigned u; } v; v.f = f;
  unsigned r = v.u + 0x7fffu + ((v.u >> 16) & 1u);
  return (short)(r >> 16);
}

__device__ __forceinline__ bf16x8 cvt8(const float* p) {
  f32x4 a = *(const f32x4*)p;
  f32x4 b = *(const f32x4*)(p + 4);
  bf16x8 v;
  v[0] = f2bf(a[0]); v[1] = f2bf(a[1]); v[2] = f2bf(a[2]); v[3] = f2bf(a[3]);
  v[4] = f2bf(b[0]); v[5] = f2bf(b[1]); v[6] = f2bf(b[2]); v[7] = f2bf(b[3]);
  return v;
}

__device__ __forceinline__ float sigm(float x) {
  return __builtin_amdgcn_rcpf(1.0f + __builtin_amdgcn_exp2f(-1.4426950408889634f * x));
}
__device__ __forceinline__ float tanh_(float x) {
  return 2.0f * __builtin_amdgcn_rcpf(1.0f + __builtin_amdgcn_exp2f(-2.8853900817779268f * x)) - 1.0f;
}

// ---------------------------------------------------------------------------
// Fused LocalRNN. Block = 16 chains (consecutive s, one batch), 8 waves.
// Phase 1: xg[r, g] = x[s0-15+r] . w_ih[g] + b_ih[g] + b_hh[g]  (r = 0..30)
//          computed via swapped MFMA into swizzled LDS (fp32, 64 KB).
// Phase 2: 16-step LSTM. Wave wv owns d-slice [16wv,16wv+16) == gate tiles
//          {wv, wv+8, wv+16, wv+24} so i,f,g,o for a (chain,d) are lane-local.
//          w_hh fragments stay in VGPRs (same array as w_ih, time-shared).
//          h (bf16) round-trips through a double-buffered swizzled LDS tile.
// Epilogue: final h via LDS transpose -> coalesced global write.
// ---------------------------------------------------------------------------
__global__ void __launch_bounds__(512, 4)
fused_rnn(const float* __restrict__ x, const float* __restrict__ w_ih,
          const float* __restrict__ w_hh, const float* __restrict__ b_ih,
          const float* __restrict__ b_hh, float* __restrict__ out) {
  __shared__ float xg_s[32 * G_N];          // 64 KB: rows 0..31, 2KB stride, swizzled
  __shared__ char hbuf[2][16 * D_N * 2];    // 8 KB: [chain][k] bf16, swizzled

  const int tid  = threadIdx.x;
  const int lane = tid & 63;
  const int wv   = tid >> 6;
  const int lm   = lane & 15;
  const int q    = lane >> 4;
  const int n0   = blockIdx.x * 16;
  const int b    = n0 >> 11;          // 2048 chains per batch
  const int s0   = n0 & (S_N - 1);

  char* xgb = (char*)xg_s;

  // ---------------- phase 1: input projection into LDS ----------------
  bf16x8 wf[4][4];   // A fragments: weight[g = tg*16+lm][k = kt*32 + q*8 + j]
#pragma unroll
  for (int i = 0; i < 4; ++i) {
    const int g = (wv + 8 * i) * 16 + lm;
#pragma unroll
    for (int kt = 0; kt < 4; ++kt)
      wf[i][kt] = cvt8(w_ih + g * D_N + kt * 32 + q * 8);
  }

  f32x4 bias[4];
#pragma unroll
  for (int i = 0; i < 4; ++i) {
    const int g0 = (wv + 8 * i) * 16 + 4 * q;
    f32x4 bi = *(const f32x4*)(b_ih + g0);
    f32x4 bh = *(const f32x4*)(b_hh + g0);
    bias[i].x = bi.x + bh.x; bias[i].y = bi.y + bh.y;
    bias[i].z = bi.z + bh.z; bias[i].w = bi.w + bh.w;
  }

#pragma unroll
  for (int rt = 0; rt < 2; ++rt) {
    const int r = rt * 16 + lm;              // xg row 0..31 (31 = scratch, never read)
    const int t = s0 - (W_N - 1) + r;        // x timestep
    const int tc = t < S_N - 1 ? t : S_N - 1;
    const bool valid = (t >= 0);
    const float* xr = x + ((long)b * S_N + tc) * D_N;
    bf16x8 xf[4];
#pragma unroll
    for (int kt = 0; kt < 4; ++kt) {
      if (valid) xf[kt] = cvt8(xr + kt * 32 + q * 8);
      else { bf16x8 z; for (int e = 0; e < 8; ++e) z[e] = 0; xf[kt] = z; }
    }
    f32x4 acc[4] = {{0,0,0,0},{0,0,0,0},{0,0,0,0},{0,0,0,0}};
#pragma unroll
    for (int i = 0; i < 4; ++i)
#pragma unroll
      for (int kt = 0; kt < 4; ++kt)
        acc[i] = __builtin_amdgcn_mfma_f32_16x16x32_bf16(wf[i][kt], xf[kt], acc[i], 0, 0, 0);
    // lane (lm,q) holds D[g = tile*16+4q+rr][row r]; store fp32 + bias, swizzled
#pragma unroll
    for (int i = 0; i < 4; ++i) {
      const int g0 = (wv + 8 * i) * 16 + 4 * q;
      const int byte = (r * 2048 + g0 * 4) ^ ((r & 7) << 4);
      f32x4 v = acc[i];
      v.x += bias[i].x; v.y += bias[i].y; v.z += bias[i].z; v.w += bias[i].w;
      *(f32x4*)(xgb + byte) = v;
    }
  }

  // reload fragment array with w_hh (time-shared registers)
#pragma unroll
  for (int i = 0; i < 4; ++i) {
    const int g = (wv + 8 * i) * 16 + lm;
#pragma unroll
    for (int kt = 0; kt < 4; ++kt)
      wf[i][kt] = cvt8(w_hh + g * D_N + kt * 32 + q * 8);
  }
  __syncthreads();

  // ---------------- phase 2: 16-step recurrence ----------------
  const int swz = (lm & 7) << 4;
  const int wr_off = (lm * 256 + (16 * wv + 4 * q) * 2) ^ swz;   // 8B h store
  int rd_off[4];
#pragma unroll
  for (int kt = 0; kt < 4; ++kt)
    rd_off[kt] = (lm * 256 + kt * 64 + q * 16) ^ swz;            // 16B h loads

  f32x4 c = {0.f, 0.f, 0.f, 0.f};
  float h[4] = {0.f, 0.f, 0.f, 0.f};

#pragma unroll
  for (int w = 0; w < W_N; ++w) {
    // gate init from LDS xg (biases folded in)
    f32x4 acc[4];
    const int row = lm + w;                  // 0..30
#pragma unroll
    for (int i = 0; i < 4; ++i) {
      const int g0 = (wv + 8 * i) * 16 + 4 * q;
      const int byte = (row * 2048 + g0 * 4) ^ ((row & 7) << 4);
      acc[i] = *(const f32x4*)(xgb + byte);
    }

    if (w > 0) {
      const char* bb = hbuf[(w - 1) & 1];
      bf16x8 hf[4];
#pragma unroll
      for (int kt = 0; kt < 4; ++kt)
        hf[kt] = *(const bf16x8*)(bb + rd_off[kt]);
#pragma unroll
      for (int i = 0; i < 4; ++i)
#pragma unroll
        for (int kt = 0; kt < 4; ++kt)
          acc[i] = __builtin_amdgcn_mfma_f32_16x16x32_bf16(wf[i][kt], hf[kt], acc[i], 0, 0, 0);
    }

    // acc[0]=i, acc[1]=f, acc[2]=g~, acc[3]=o  for d = 16wv+4q+rr, chain = lm
#pragma unroll
    for (int r = 0; r < 4; ++r) {
      float cn = sigm(acc[1][r]) * c[r] + sigm(acc[0][r]) * tanh_(acc[2][r]);
      c[r] = cn;
      h[r] = sigm(acc[3][r]) * tanh_(cn);
    }

    if (w < W_N - 1) {   // publish h (bf16) for next step
      unsigned lo = ((unsigned)(unsigned short)f2bf(h[0])) |
                    (((unsigned)(unsigned short)f2bf(h[1])) << 16);
      unsigned hi = ((unsigned)(unsigned short)f2bf(h[2])) |
                    (((unsigned)(unsigned short)f2bf(h[3])) << 16);
      u32x2 v = {lo, hi};
      *(u32x2*)(&hbuf[w & 1][wr_off]) = v;
    }
    __syncthreads();
  }

  // ---------------- epilogue: coalesced out via LDS transpose ----------------
  {  // write final h (fp32) to xg rows 0..15 (all xg reads completed above)
    const int byte = (lm * 2048 + (16 * wv + 4 * q) * 4) ^ ((lm & 7) << 4);
    f32x4 hv = {h[0], h[1], h[2], h[3]};
    *(f32x4*)(xgb + byte) = hv;
  }
  __syncthreads();
  {
    const int chain = tid >> 5;              // 16 chains x 32 threads
    const int d4 = (tid & 31) * 4;
    const int byte = (chain * 2048 + d4 * 4) ^ ((chain & 7) << 4);
    f32x4 v = *(const f32x4*)(xgb + byte);
    *(f32x4*)(out + (long)(n0 + chain) * D_N + d4) = v;
  }
}

// ---------------------------------------------------------------------------
extern "C" void kernel_launch(void* const* d_in, const int* in_sizes, int n_in,
                              void* d_out, int out_size, void* d_ws, size_t ws_size,
                              hipStream_t stream) {
  const float* x    = (const float*)d_in[0];
  const float* w_ih = (const float*)d_in[1];
  const float* w_hh = (const float*)d_in[2];
  const float* b_ih = (const float*)d_in[3];
  const float* b_hh = (const float*)d_in[4];
  float* out = (float*)d_out;

  fused_rnn<<<(B_N * S_N) / 16, 512, 0, stream>>>(x, w_ih, w_hh, b_ih, b_hh, out);
}

// Round 4
// 196.750 us; speedup vs baseline: 1.2371x; 1.2371x over previous
//
#include <hip/hip_runtime.h>

typedef __attribute__((ext_vector_type(8))) short bf16x8;
typedef __attribute__((ext_vector_type(4))) float f32x4;
typedef __attribute__((ext_vector_type(2))) unsigned int u32x2;

#define B_N 8
#define S_N 2048
#define D_N 128
#define W_N 16
#define G_N 512

// round-to-nearest-even fp32 -> bf16
__device__ __forceinline__ short f2bf(float f) {
  union { float f; unsigned u; } v; v.f = f;
  unsigned r = v.u + 0x7fffu + ((v.u >> 16) & 1u);
  return (short)(r >> 16);
}

__device__ __forceinline__ bf16x8 cvt8(const float* p) {
  f32x4 a = *(const f32x4*)p;
  f32x4 b = *(const f32x4*)(p + 4);
  bf16x8 v;
  v[0] = f2bf(a[0]); v[1] = f2bf(a[1]); v[2] = f2bf(a[2]); v[3] = f2bf(a[3]);
  v[4] = f2bf(b[0]); v[5] = f2bf(b[1]); v[6] = f2bf(b[2]); v[7] = f2bf(b[3]);
  return v;
}

__device__ __forceinline__ float sigm(float x) {
  return __builtin_amdgcn_rcpf(1.0f + __builtin_amdgcn_exp2f(-1.4426950408889634f * x));
}
__device__ __forceinline__ float tanh_(float x) {
  return 2.0f * __builtin_amdgcn_rcpf(1.0f + __builtin_amdgcn_exp2f(-2.8853900817779268f * x)) - 1.0f;
}

// ---------------------------------------------------------------------------
// Fused LocalRNN. Block = 16 chains (consecutive s, one batch), 8 waves.
// Phase 1: xg[r, g] = x[s0-15+r] . w_ih[g] + b_ih[g] + b_hh[g]  (r = 0..30)
//          computed via swapped MFMA into swizzled LDS (fp32, 64 KB).
// Phase 2: 16-step LSTM. Wave wv owns d-slice [16wv,16wv+16) == gate tiles
//          {wv, wv+8, wv+16, wv+24} so i,f,g,o for a (chain,d) are lane-local.
//          w_hh fragments stay in VGPRs (same array as w_ih, time-shared).
//          h (bf16) round-trips through a double-buffered swizzled LDS tile.
// Epilogue: final h via LDS transpose -> coalesced global write.
//
// __launch_bounds__(512, 2): unified VGPR+AGPR cap 256/wave. The live set
// (wf 64 + hf 16 + acc 16 + c/h/addr ~30 = ~130) MUST NOT SPILL — at (512,4)
// the 128-reg cap spilled wf and generated 490 MB/dispatch of scratch HBM
// traffic (R3 counters: FETCH 165 MB, WRITE 313 MB).
// ---------------------------------------------------------------------------
__global__ void __launch_bounds__(512, 2)
fused_rnn(const float* __restrict__ x, const float* __restrict__ w_ih,
          const float* __restrict__ w_hh, const float* __restrict__ b_ih,
          const float* __restrict__ b_hh, float* __restrict__ out) {
  __shared__ float xg_s[32 * G_N];          // 64 KB: rows 0..31, 2KB stride, swizzled
  __shared__ char hbuf[2][16 * D_N * 2];    // 8 KB: [chain][k] bf16, swizzled

  const int tid  = threadIdx.x;
  const int lane = tid & 63;
  const int wv   = tid >> 6;
  const int lm   = lane & 15;
  const int q    = lane >> 4;
  const int n0   = blockIdx.x * 16;
  const int b    = n0 >> 11;          // 2048 chains per batch
  const int s0   = n0 & (S_N - 1);

  char* xgb = (char*)xg_s;

  // ---------------- phase 1: input projection into LDS ----------------
  bf16x8 wf[4][4];   // A fragments: weight[g = tg*16+lm][k = kt*32 + q*8 + j]
#pragma unroll
  for (int i = 0; i < 4; ++i) {
    const int g = (wv + 8 * i) * 16 + lm;
#pragma unroll
    for (int kt = 0; kt < 4; ++kt)
      wf[i][kt] = cvt8(w_ih + g * D_N + kt * 32 + q * 8);
  }

  f32x4 bias[4];
#pragma unroll
  for (int i = 0; i < 4; ++i) {
    const int g0 = (wv + 8 * i) * 16 + 4 * q;
    f32x4 bi = *(const f32x4*)(b_ih + g0);
    f32x4 bh = *(const f32x4*)(b_hh + g0);
    bias[i].x = bi.x + bh.x; bias[i].y = bi.y + bh.y;
    bias[i].z = bi.z + bh.z; bias[i].w = bi.w + bh.w;
  }

#pragma unroll
  for (int rt = 0; rt < 2; ++rt) {
    const int r = rt * 16 + lm;              // xg row 0..31 (31 = scratch, never read)
    const int t = s0 - (W_N - 1) + r;        // x timestep
    const int tc = t < S_N - 1 ? t : S_N - 1;
    const bool valid = (t >= 0);
    const float* xr = x + ((long)b * S_N + tc) * D_N;
    bf16x8 xf[4];
#pragma unroll
    for (int kt = 0; kt < 4; ++kt) {
      if (valid) xf[kt] = cvt8(xr + kt * 32 + q * 8);
      else { bf16x8 z; for (int e = 0; e < 8; ++e) z[e] = 0; xf[kt] = z; }
    }
    f32x4 acc[4] = {{0,0,0,0},{0,0,0,0},{0,0,0,0},{0,0,0,0}};
#pragma unroll
    for (int i = 0; i < 4; ++i)
#pragma unroll
      for (int kt = 0; kt < 4; ++kt)
        acc[i] = __builtin_amdgcn_mfma_f32_16x16x32_bf16(wf[i][kt], xf[kt], acc[i], 0, 0, 0);
    // lane (lm,q) holds D[g = tile*16+4q+rr][row r]; store fp32 + bias, swizzled
#pragma unroll
    for (int i = 0; i < 4; ++i) {
      const int g0 = (wv + 8 * i) * 16 + 4 * q;
      const int byte = (r * 2048 + g0 * 4) ^ ((r & 7) << 4);
      f32x4 v = acc[i];
      v.x += bias[i].x; v.y += bias[i].y; v.z += bias[i].z; v.w += bias[i].w;
      *(f32x4*)(xgb + byte) = v;
    }
  }

  // reload fragment array with w_hh (time-shared registers)
#pragma unroll
  for (int i = 0; i < 4; ++i) {
    const int g = (wv + 8 * i) * 16 + lm;
#pragma unroll
    for (int kt = 0; kt < 4; ++kt)
      wf[i][kt] = cvt8(w_hh + g * D_N + kt * 32 + q * 8);
  }
  __syncthreads();

  // ---------------- phase 2: 16-step recurrence ----------------
  const int swz = (lm & 7) << 4;
  const int wr_off = (lm * 256 + (16 * wv + 4 * q) * 2) ^ swz;   // 8B h store
  int rd_off[4];
#pragma unroll
  for (int kt = 0; kt < 4; ++kt)
    rd_off[kt] = (lm * 256 + kt * 64 + q * 16) ^ swz;            // 16B h loads

  f32x4 c = {0.f, 0.f, 0.f, 0.f};
  float h[4] = {0.f, 0.f, 0.f, 0.f};

#pragma unroll
  for (int w = 0; w < W_N; ++w) {
    // gate init from LDS xg (biases folded in)
    f32x4 acc[4];
    const int row = lm + w;                  // 0..30
#pragma unroll
    for (int i = 0; i < 4; ++i) {
      const int g0 = (wv + 8 * i) * 16 + 4 * q;
      const int byte = (row * 2048 + g0 * 4) ^ ((row & 7) << 4);
      acc[i] = *(const f32x4*)(xgb + byte);
    }

    if (w > 0) {
      const char* bb = hbuf[(w - 1) & 1];
      bf16x8 hf[4];
#pragma unroll
      for (int kt = 0; kt < 4; ++kt)
        hf[kt] = *(const bf16x8*)(bb + rd_off[kt]);
#pragma unroll
      for (int i = 0; i < 4; ++i)
#pragma unroll
        for (int kt = 0; kt < 4; ++kt)
          acc[i] = __builtin_amdgcn_mfma_f32_16x16x32_bf16(wf[i][kt], hf[kt], acc[i], 0, 0, 0);
    }

    // acc[0]=i, acc[1]=f, acc[2]=g~, acc[3]=o  for d = 16wv+4q+rr, chain = lm
#pragma unroll
    for (int r = 0; r < 4; ++r) {
      float cn = sigm(acc[1][r]) * c[r] + sigm(acc[0][r]) * tanh_(acc[2][r]);
      c[r] = cn;
      h[r] = sigm(acc[3][r]) * tanh_(cn);
    }

    if (w < W_N - 1) {   // publish h (bf16) for next step
      unsigned lo = ((unsigned)(unsigned short)f2bf(h[0])) |
                    (((unsigned)(unsigned short)f2bf(h[1])) << 16);
      unsigned hi = ((unsigned)(unsigned short)f2bf(h[2])) |
                    (((unsigned)(unsigned short)f2bf(h[3])) << 16);
      u32x2 v = {lo, hi};
      *(u32x2*)(&hbuf[w & 1][wr_off]) = v;
    }
    __syncthreads();
  }

  // ---------------- epilogue: coalesced out via LDS transpose ----------------
  {  // write final h (fp32) to xg rows 0..15 (all xg reads completed above)
    const int byte = (lm * 2048 + (16 * wv + 4 * q) * 4) ^ ((lm & 7) << 4);
    f32x4 hv = {h[0], h[1], h[2], h[3]};
    *(f32x4*)(xgb + byte) = hv;
  }
  __syncthreads();
  {
    const int chain = tid >> 5;              // 16 chains x 32 threads
    const int d4 = (tid & 31) * 4;
    const int byte = (chain * 2048 + d4 * 4) ^ ((chain & 7) << 4);
    f32x4 v = *(const f32x4*)(xgb + byte);
    *(f32x4*)(out + (long)(n0 + chain) * D_N + d4) = v;
  }
}

// ---------------------------------------------------------------------------
extern "C" void kernel_launch(void* const* d_in, const int* in_sizes, int n_in,
                              void* d_out, int out_size, void* d_ws, size_t ws_size,
                              hipStream_t stream) {
  const float* x    = (const float*)d_in[0];
  const float* w_ih = (const float*)d_in[1];
  const float* w_hh = (const float*)d_in[2];
  const float* b_ih = (const float*)d_in[3];
  const float* b_hh = (const float*)d_in[4];
  float* out = (float*)d_out;

  fused_rnn<<<(B_N * S_N) / 16, 512, 0, stream>>>(x, w_ih, w_hh, b_ih, b_hh, out);
}

// Round 6
// 144.904 us; speedup vs baseline: 1.6798x; 1.3578x over previous
//
#include <hip/hip_runtime.h>

typedef __attribute__((ext_vector_type(8))) short bf16x8;
typedef __attribute__((ext_vector_type(4))) float f32x4;
typedef __attribute__((ext_vector_type(4))) _Float16 f16x4;
typedef __attribute__((ext_vector_type(2))) unsigned int u32x2;

#define B_N 8
#define S_N 2048
#define D_N 128
#define W_N 16
#define G_N 512
#define CH 64      /* chains per block */
#define ROWS 80    /* xg rows: 0..78 used (CH+W-1=79), 79 scratch */

// round-to-nearest-even fp32 -> bf16
__device__ __forceinline__ short f2bf(float f) {
  union { float f; unsigned u; } v; v.f = f;
  unsigned r = v.u + 0x7fffu + ((v.u >> 16) & 1u);
  return (short)(r >> 16);
}

__device__ __forceinline__ bf16x8 cvt8(const float* p) {
  f32x4 a = *(const f32x4*)p;
  f32x4 b = *(const f32x4*)(p + 4);
  bf16x8 v;
  v[0] = f2bf(a[0]); v[1] = f2bf(a[1]); v[2] = f2bf(a[2]); v[3] = f2bf(a[3]);
  v[4] = f2bf(b[0]); v[5] = f2bf(b[1]); v[6] = f2bf(b[2]); v[7] = f2bf(b[3]);
  return v;
}

__device__ __forceinline__ float sigm(float x) {
  return __builtin_amdgcn_rcpf(1.0f + __builtin_amdgcn_exp2f(-1.4426950408889634f * x));
}
__device__ __forceinline__ float tanh_(float x) {
  return 2.0f * __builtin_amdgcn_rcpf(1.0f + __builtin_amdgcn_exp2f(-2.8853900817779268f * x)) - 1.0f;
}

// ---------------------------------------------------------------------------
// Fused LocalRNN, 64 chains/block, 256 blocks == 1 block/CU, single round.
// Phase 1: xg[r,g] = x[s0-15+r].w_ih[g] + b_ih[g] + b_hh[g], r=0..79, stored
//          f16 in swizzled LDS (80 KB). Swapped MFMA: D[g][row].
// Phase 2: 16-step LSTM. Wave wv owns gate tiles {wv,wv+8,wv+16,wv+24} so
//          i,f,g,o for one (chain,d) are lane-local. Per step, 4 chain-groups
//          of 16 processed sequentially (hf/acc regs reused). w_hh fragments
//          live in VGPRs (time-shared with w_ih). h round-trips bf16 through
//          a double-buffered swizzled LDS tile (2x16 KB), 1 barrier/step.
// Epilogue: final h via LDS transpose -> fully coalesced fp32 out.
// __launch_bounds__(512,2): 256-reg cap; live set ~170 regs MUST NOT SPILL
// (R3: spill => 490 MB of scratch HBM traffic; verify WRITE_SIZE ~ 8 MB).
// ---------------------------------------------------------------------------
__global__ void __launch_bounds__(512, 2)
fused_rnn(const float* __restrict__ x, const float* __restrict__ w_ih,
          const float* __restrict__ w_hh, const float* __restrict__ b_ih,
          const float* __restrict__ b_hh, float* __restrict__ out) {
  __shared__ char xg_s[ROWS * 1024];        // 80 KB: f16 [row][gate], swizzled
  __shared__ char hbuf[2][CH * 256];        // 2x16 KB: bf16 [chain][k], swizzled

  const int tid  = threadIdx.x;
  const int lane = tid & 63;
  const int wv   = tid >> 6;
  const int lm   = lane & 15;
  const int q    = lane >> 4;
  const int n0   = blockIdx.x * CH;
  const int b    = n0 >> 11;                // 2048 chains per batch, CH | 2048
  const int s0   = n0 & (S_N - 1);

  // ---------------- phase 1: input projection into LDS (f16) ----------------
  bf16x8 wf[4][4];   // A fragments: weight[g = tg*16+lm][k = kt*32 + q*8 + j]
#pragma unroll
  for (int i = 0; i < 4; ++i) {
    const int g = (wv + 8 * i) * 16 + lm;
#pragma unroll
    for (int kt = 0; kt < 4; ++kt)
      wf[i][kt] = cvt8(w_ih + g * D_N + kt * 32 + q * 8);
  }

  f32x4 bias[4];
#pragma unroll
  for (int i = 0; i < 4; ++i) {
    const int g0 = (wv + 8 * i) * 16 + 4 * q;
    f32x4 bi = *(const f32x4*)(b_ih + g0);
    f32x4 bh = *(const f32x4*)(b_hh + g0);
    bias[i].x = bi.x + bh.x; bias[i].y = bi.y + bh.y;
    bias[i].z = bi.z + bh.z; bias[i].w = bi.w + bh.w;
  }

#pragma unroll
  for (int rg = 0; rg < 5; ++rg) {
    const int r = rg * 16 + lm;              // xg row 0..79 (79 = scratch)
    const int t = s0 - (W_N - 1) + r;        // x timestep
    int tc = t < 0 ? 0 : t;
    tc = tc < S_N - 1 ? tc : S_N - 1;        // clamp (r=79 on last block)
    const bool valid = (t >= 0);
    const float* xr = x + ((long)b * S_N + tc) * D_N;
    bf16x8 xf[4];
#pragma unroll
    for (int kt = 0; kt < 4; ++kt) {
      if (valid) xf[kt] = cvt8(xr + kt * 32 + q * 8);
      else { bf16x8 z; for (int e = 0; e < 8; ++e) z[e] = 0; xf[kt] = z; }
    }
    f32x4 acc[4] = {{0,0,0,0},{0,0,0,0},{0,0,0,0},{0,0,0,0}};
#pragma unroll
    for (int i = 0; i < 4; ++i)
#pragma unroll
      for (int kt = 0; kt < 4; ++kt)
        acc[i] = __builtin_amdgcn_mfma_f32_16x16x32_bf16(wf[i][kt], xf[kt], acc[i], 0, 0, 0);
    // lane (lm,q) holds D[g = tile*16+4q+rr][row r]; store f16 + bias, swizzled
#pragma unroll
    for (int i = 0; i < 4; ++i) {
      const int g0 = (wv + 8 * i) * 16 + 4 * q;
      const int byte = (r * 1024 + g0 * 2) ^ ((r & 7) << 4);
      f16x4 hv;
      hv[0] = (_Float16)(acc[i][0] + bias[i].x);
      hv[1] = (_Float16)(acc[i][1] + bias[i].y);
      hv[2] = (_Float16)(acc[i][2] + bias[i].z);
      hv[3] = (_Float16)(acc[i][3] + bias[i].w);
      *(f16x4*)(xg_s + byte) = hv;
    }
  }

  // reload fragment array with w_hh (time-shared registers)
#pragma unroll
  for (int i = 0; i < 4; ++i) {
    const int g = (wv + 8 * i) * 16 + lm;
#pragma unroll
    for (int kt = 0; kt < 4; ++kt)
      wf[i][kt] = cvt8(w_hh + g * D_N + kt * 32 + q * 8);
  }
  __syncthreads();

  // ---------------- phase 2: 16-step recurrence, 4 chain-groups ----------------
  // chain = cg*16 + lm; chain&7 == lm&7, so swizzle is cg-independent and
  // cg*4096 offsets are above the XOR bits (safe to add).
  const int swz = (lm & 7) << 4;
  const int wrb = (lm * 256 + (16 * wv + 4 * q) * 2) ^ swz;     // 8B h store
  int rdb[4];
#pragma unroll
  for (int kt = 0; kt < 4; ++kt)
    rdb[kt] = (lm * 256 + kt * 64 + q * 16) ^ swz;              // 16B h loads

  f32x4 c[4] = {{0,0,0,0},{0,0,0,0},{0,0,0,0},{0,0,0,0}};
  f32x4 hfin[4];

#pragma unroll
  for (int w = 0; w < W_N; ++w) {
#pragma unroll
    for (int cg = 0; cg < 4; ++cg) {
      // gate init from f16 xg (biases folded in)
      const int row = cg * 16 + lm + w;      // 0..78
      f32x4 acc[4];
#pragma unroll
      for (int i = 0; i < 4; ++i) {
        const int g0 = (wv + 8 * i) * 16 + 4 * q;
        const int byte = (row * 1024 + g0 * 2) ^ ((row & 7) << 4);
        f16x4 xv = *(const f16x4*)(xg_s + byte);
        acc[i][0] = (float)xv[0]; acc[i][1] = (float)xv[1];
        acc[i][2] = (float)xv[2]; acc[i][3] = (float)xv[3];
      }

      if (w > 0) {
        const char* bb = hbuf[(w - 1) & 1] + cg * 4096;
        bf16x8 hf[4];
#pragma unroll
        for (int kt = 0; kt < 4; ++kt)
          hf[kt] = *(const bf16x8*)(bb + rdb[kt]);
#pragma unroll
        for (int i = 0; i < 4; ++i)
#pragma unroll
          for (int kt = 0; kt < 4; ++kt)
            acc[i] = __builtin_amdgcn_mfma_f32_16x16x32_bf16(wf[i][kt], hf[kt], acc[i], 0, 0, 0);
      }

      // acc[0]=i, acc[1]=f, acc[2]=g~, acc[3]=o  for d=16wv+4q+r, chain=cg*16+lm
      float hr[4];
#pragma unroll
      for (int r = 0; r < 4; ++r) {
        float cn = sigm(acc[1][r]) * c[cg][r] + sigm(acc[0][r]) * tanh_(acc[2][r]);
        c[cg][r] = cn;
        hr[r] = sigm(acc[3][r]) * tanh_(cn);
      }

      if (w < W_N - 1) {   // publish h (bf16) for next step
        unsigned lo = ((unsigned)(unsigned short)f2bf(hr[0])) |
                      (((unsigned)(unsigned short)f2bf(hr[1])) << 16);
        unsigned hi = ((unsigned)(unsigned short)f2bf(hr[2])) |
                      (((unsigned)(unsigned short)f2bf(hr[3])) << 16);
        u32x2 v = {lo, hi};
        *(u32x2*)(&hbuf[w & 1][cg * 4096 + wrb]) = v;
      } else {
        hfin[cg][0] = hr[0]; hfin[cg][1] = hr[1];
        hfin[cg][2] = hr[2]; hfin[cg][3] = hr[3];
      }
    }
    __syncthreads();   // h published; also (at w=15) all xg reads complete
  }

  // ---------------- epilogue: coalesced out via LDS transpose ----------------
  // reuse xg_s: f32 [chain][d], byte = (chain*512 + d*4) ^ ((chain&7)<<4)
#pragma unroll
  for (int cg = 0; cg < 4; ++cg) {
    const int chain = cg * 16 + lm;
    const int byte = (chain * 512 + (16 * wv + 4 * q) * 4) ^ swz;
    *(f32x4*)(xg_s + byte) = hfin[cg];
  }
  __syncthreads();
#pragma unroll
  for (int p = 0; p < 4; ++p) {
    const int idx = p * 512 + tid;           // 0..2047
    const int chain = idx >> 5;
    const int d4 = (idx & 31) * 4;
    const int byte = (chain * 512 + d4 * 4) ^ ((chain & 7) << 4);
    f32x4 v = *(const f32x4*)(xg_s + byte);
    *(f32x4*)(out + (long)(n0 + chain) * D_N + d4) = v;
  }
}

// ---------------------------------------------------------------------------
extern "C" void kernel_launch(void* const* d_in, const int* in_sizes, int n_in,
                              void* d_out, int out_size, void* d_ws, size_t ws_size,
                              hipStream_t stream) {
  const float* x    = (const float*)d_in[0];
  const float* w_ih = (const float*)d_in[1];
  const float* w_hh = (const float*)d_in[2];
  const float* b_ih = (const float*)d_in[3];
  const float* b_hh = (const float*)d_in[4];
  float* out = (float*)d_out;

  fused_rnn<<<(B_N * S_N) / CH, 512, 0, stream>>>(x, w_ih, w_hh, b_ih, b_hh, out);
}